// Round 20
// baseline (229.400 us; speedup 1.0000x reference)
//
#include <hip/hip_runtime.h>

#define BN_ 256
#define T_  128
#define F_  16
#define H_  64

using f16x8   = __attribute__((ext_vector_type(8))) _Float16;
using f32x4   = __attribute__((ext_vector_type(4))) float;
using ushort8 = __attribute__((ext_vector_type(8))) unsigned short;

__device__ __forceinline__ float elu_(float x) { return x > 0.f ? x : __expf(x) - 1.f; }
__device__ __forceinline__ unsigned short f2h(float x) {
    union { _Float16 h; unsigned short u; } v; v.h = (_Float16)x; return v.u;
}
__device__ __forceinline__ float h2f(unsigned short u) {
    union { unsigned short u; _Float16 h; } v; v.u = u; return (float)v.h;
}
__device__ __forceinline__ unsigned pk2(float a, float b) {
    auto h = __builtin_amdgcn_cvt_pkrtz(a, b);
    unsigned u; __builtin_memcpy(&u, &h, 4); return u;
}
__device__ __forceinline__ void st4h(unsigned short* p, float a, float b, float c, float d) {
    uint2 v; v.x = pk2(a, b); v.y = pk2(c, d);
    *reinterpret_cast<uint2*>(p) = v;
}

// ---------------- prep: conv weights -> fp16 transposed [l][f][g][192]; block 48 does small tensors ----------------
__global__ __launch_bounds__(256) void prep_all(const float* __restrict__ Wt0,
                                                const float* __restrict__ Wt1,
                                                const float* __restrict__ Wt2,
                                                const float* __restrict__ adjG,
                                                const float* __restrict__ W_G,
                                                const float* __restrict__ W_g,
                                                unsigned short* __restrict__ pw,
                                                unsigned short* __restrict__ padj,
                                                unsigned short* __restrict__ pWG,
                                                unsigned short* __restrict__ pWg)
{
    const int tid = threadIdx.x;
    if (blockIdx.x == 48) {
        for (int idx = tid; idx < 4608; idx += 256) {
            int m = idx / 72, n = idx - m * 72;
            padj[idx] = (n < 64) ? f2h(adjG[m * 64 + n]) : (unsigned short)0;
        }
        for (int idx = tid; idx < 6656; idx += 256) {
            int g = idx / 104, k = idx - g * 104;
            pWG[idx] = (k < 80) ? f2h(W_G[k * 64 + g]) : (unsigned short)0;
        }
        for (int idx = tid; idx < 6656; idx += 256) {
            int g = idx / 104, k = idx - g * 104;
            pWg[idx] = (k < 72) ? f2h(W_g[k * 64 + g]) : (unsigned short)0;
        }
        return;
    }
    __shared__ unsigned short sW[64 * 200];
    const int lf = blockIdx.x, l = lf >> 4, f = lf & 15;
    const float* W = (l == 0) ? Wt0 : ((l == 1) ? Wt1 : Wt2);

    for (int idx = tid; idx < 3 * 4096; idx += 256) {
        int tap = idx >> 12, rem = idx & 4095;
        int h = rem >> 6, g = rem & 63;
        sW[g * 200 + tap * 64 + h] = f2h(W[(size_t)(tap * 16 + f) * 4096 + rem]);
    }
    __syncthreads();
    for (int idx = tid; idx < 64 * 24; idx += 256) {
        int g = idx / 24, k8 = idx - g * 24;
        *reinterpret_cast<ushort8*>(&pw[((size_t)lf * 64 + g) * 192 + k8 * 8]) =
            *reinterpret_cast<const ushort8*>(&sW[g * 200 + k8 * 8]);
    }
}

// ---------------- fused: tconv x3 (+LN_t) + dense_G per (bn,f); 8 waves; 2-way-bank strides ----------------
// tile stride 88 (44 dw ≡ 12 mod 32 -> 2-way), sW stride 216 (108 dw ≡ 12 -> 2-way)
__global__ __launch_bounds__(512) void conv_chain(const float* __restrict__ in,
                                                  const unsigned short* __restrict__ pw,
                                                  const float* __restrict__ bt0,
                                                  const float* __restrict__ bt1,
                                                  const float* __restrict__ bt2,
                                                  const float* __restrict__ gamma,
                                                  const float* __restrict__ beta,
                                                  const float* __restrict__ embs_G,
                                                  const unsigned short* __restrict__ pWG,
                                                  const float* __restrict__ b_G,
                                                  unsigned short* __restrict__ d1)
{
    __shared__ __align__(16) char smem[53120];
    unsigned short* tile = (unsigned short*)smem;             // [136][88] = 23936 B
    unsigned short* sW   = (unsigned short*)(smem + 23936);   // [64][216] = 27648 B -> 51584
    float*          sCst = (float*)(smem + 51584);            // [6][64] = 1536 -> 53120
    unsigned short* sA1  = (unsigned short*)smem;             // [128][104] overlay (0..26624)
    unsigned short* sWG  = (unsigned short*)(smem + 26624);   // [64][104] overlay (26624..39936)

    const int f   = blockIdx.x & 15;
    const int bn  = blockIdx.x >> 4;
    const int tid = threadIdx.x;
    const int lane = tid & 63, w = tid >> 6;
    const int r16 = lane & 15, q = lane >> 4;

    const int et = tid >> 2, ee = (tid & 3) * 4;
    float4 ereg = *reinterpret_cast<const float4*>(
        embs_G + ((((size_t)bn * T_ + et) * F_ + f) * 16 + ee));

    if (tid < 64) {
        sCst[0 * 64 + tid] = bt0[f * 64 + tid];
        sCst[1 * 64 + tid] = bt1[f * 64 + tid];
        sCst[2 * 64 + tid] = bt2[f * 64 + tid];
        sCst[3 * 64 + tid] = gamma[tid];
        sCst[4 * 64 + tid] = beta[tid];
        sCst[5 * 64 + tid] = b_G[tid];
    }
    // halo rows (0..3, 132..135) zero
    if (tid < 128) {
        int hr = tid >> 4;
        int r = (hr < 4) ? hr : 128 + hr;
        uint2 z = {0, 0};
        *reinterpret_cast<uint2*>(&tile[r * 88 + (tid & 15) * 4]) = z;
    }
    // body rows: exactly 4 branch-free iterations
#pragma unroll
    for (int it = 0; it < 4; ++it) {
        int idx = it * 512 + tid;
        int r = idx >> 4, h4 = (idx & 15) * 4;
        float4 x = *reinterpret_cast<const float4*>(in + (((size_t)bn * T_ + r) * F_ + f) * H_ + h4);
        st4h(&tile[(r + 4) * 88 + h4], x.x, x.y, x.z, x.w);
    }
    {
        const unsigned short* wsrc = pw + (size_t)f * 64 * 192;
        for (int idx = tid; idx < 1536; idx += 512) {
            int g = idx / 24, k8 = idx - g * 24;
            *reinterpret_cast<ushort8*>(&sW[g * 216 + k8 * 8]) =
                *reinterpret_cast<const ushort8*>(&wsrc[g * 192 + k8 * 8]);
        }
    }
    __syncthreads();

    float vv[4][4];

#pragma unroll
    for (int l = 0; l < 3; ++l) {
        const int dil = 1 << l;

        ushort8 wreg[3];
        if (l < 2) {
            const unsigned short* wsrc = pw + ((size_t)((l + 1) * 16 + f) * 64) * 192;
#pragma unroll
            for (int j = 0; j < 3; ++j) {
                int idx = j * 512 + tid, g = idx / 24, k8 = idx - g * 24;
                wreg[j] = *reinterpret_cast<const ushort8*>(&wsrc[g * 192 + k8 * 8]);
            }
        }
        ushort8 wgreg[2];
        if (l == 2) {
#pragma unroll
            for (int j = 0; j < 2; ++j) {
                int idx = j * 512 + tid;
                if (idx < 832) wgreg[j] = reinterpret_cast<const ushort8*>(pWG)[idx];
            }
        }

        f32x4 acc[4];
#pragma unroll
        for (int j = 0; j < 4; j++) acc[j] = {0.f, 0.f, 0.f, 0.f};

#pragma unroll
        for (int tap = 0; tap < 3; ++tap) {
            const int row0 = w * 16 + r16 + 4 + (tap - 1) * dil;
#pragma unroll
            for (int ks = 0; ks < 2; ++ks) {
                const int ko = ks * 32 + q * 8;
                f16x8 a0 = *reinterpret_cast<const f16x8*>(&tile[row0 * 88 + ko]);
                const int kb = tap * 64 + ko;
                f16x8 b0 = *reinterpret_cast<const f16x8*>(&sW[(r16     ) * 216 + kb]);
                f16x8 b1 = *reinterpret_cast<const f16x8*>(&sW[(r16 + 16) * 216 + kb]);
                f16x8 b2 = *reinterpret_cast<const f16x8*>(&sW[(r16 + 32) * 216 + kb]);
                f16x8 b3 = *reinterpret_cast<const f16x8*>(&sW[(r16 + 48) * 216 + kb]);
                acc[0] = __builtin_amdgcn_mfma_f32_16x16x32_f16(b0, a0, acc[0], 0, 0, 0);
                acc[1] = __builtin_amdgcn_mfma_f32_16x16x32_f16(b1, a0, acc[1], 0, 0, 0);
                acc[2] = __builtin_amdgcn_mfma_f32_16x16x32_f16(b2, a0, acc[2], 0, 0, 0);
                acc[3] = __builtin_amdgcn_mfma_f32_16x16x32_f16(b3, a0, acc[3], 0, 0, 0);
            }
        }

#pragma unroll
        for (int gt = 0; gt < 4; ++gt) {
            float4 b4 = *reinterpret_cast<const float4*>(&sCst[l * 64 + gt * 16 + q * 4]);
#pragma unroll
            for (int r = 0; r < 4; ++r) vv[gt][r] = elu_(acc[gt][r] + ((const float*)&b4)[r]);
        }
        if (l == 2) {
            float s = 0.f, qq = 0.f;
#pragma unroll
            for (int gt = 0; gt < 4; ++gt)
#pragma unroll
                for (int r = 0; r < 4; ++r) { float v = vv[gt][r]; s += v; qq += v * v; }
            s += __shfl_xor(s, 16, 64); qq += __shfl_xor(qq, 16, 64);
            s += __shfl_xor(s, 32, 64); qq += __shfl_xor(qq, 32, 64);
            float mean = s * (1.f / 64.f);
            float var  = qq * (1.f / 64.f) - mean * mean;
            float rstd = rsqrtf(var + 1e-5f);
#pragma unroll
            for (int gt = 0; gt < 4; ++gt) {
                float4 g4 = *reinterpret_cast<const float4*>(&sCst[3 * 64 + gt * 16 + q * 4]);
                float4 be4 = *reinterpret_cast<const float4*>(&sCst[4 * 64 + gt * 16 + q * 4]);
#pragma unroll
                for (int r = 0; r < 4; ++r)
                    vv[gt][r] = (vv[gt][r] - mean) * rstd * ((const float*)&g4)[r] + ((const float*)&be4)[r];
            }
        }
        __syncthreads();

        if (l < 2) {
            const int t = w * 16 + r16;
#pragma unroll
            for (int gt = 0; gt < 4; ++gt)
                st4h(&tile[(t + 4) * 88 + gt * 16 + q * 4],
                     vv[gt][0], vv[gt][1], vv[gt][2], vv[gt][3]);
#pragma unroll
            for (int j = 0; j < 3; ++j) {
                int idx = j * 512 + tid, g = idx / 24, k8 = idx - g * 24;
                *reinterpret_cast<ushort8*>(&sW[g * 216 + k8 * 8]) = wreg[j];
            }
            __syncthreads();
        } else {
            const int t = w * 16 + r16;
#pragma unroll
            for (int gt = 0; gt < 4; ++gt)
                st4h(&sA1[t * 104 + gt * 16 + q * 4],
                     vv[gt][0], vv[gt][1], vv[gt][2], vv[gt][3]);
            st4h(&sA1[et * 104 + 64 + ee], ereg.x, ereg.y, ereg.z, ereg.w);
            if (tid < 256) {
                int r = tid >> 1, half = tid & 1;
                ushort8 z = {0,0,0,0,0,0,0,0};
                *reinterpret_cast<ushort8*>(&sA1[r * 104 + 80 + half * 8]) = z;
            }
#pragma unroll
            for (int j = 0; j < 2; ++j) {
                int idx = j * 512 + tid;
                if (idx < 832) reinterpret_cast<ushort8*>(sWG)[idx] = wgreg[j];
            }
            __syncthreads();
        }
    }

    f32x4 dacc[4];
#pragma unroll
    for (int j = 0; j < 4; j++) dacc[j] = {0.f, 0.f, 0.f, 0.f};

#pragma unroll
    for (int ks = 0; ks < 3; ++ks) {
        const int ko = ks * 32 + q * 8;
        f16x8 a0 = *reinterpret_cast<const f16x8*>(&sA1[(w * 16 + r16) * 104 + ko]);
#pragma unroll
        for (int gt = 0; gt < 4; ++gt) {
            f16x8 bb = *reinterpret_cast<const f16x8*>(&sWG[(gt * 16 + r16) * 104 + ko]);
            dacc[gt] = __builtin_amdgcn_mfma_f32_16x16x32_f16(bb, a0, dacc[gt], 0, 0, 0);
        }
    }

    {
        const int t = w * 16 + r16;
        const int b = bn >> 6, n = bn & 63;
        const size_t ob = ((((size_t)b * T_ + t) * F_ + f) << 12) + (size_t)n * 64;
#pragma unroll
        for (int gt = 0; gt < 4; ++gt) {
            float4 b4 = *reinterpret_cast<const float4*>(&sCst[5 * 64 + gt * 16 + q * 4]);
            st4h(&d1[ob + gt * 16 + q * 4],
                 elu_(dacc[gt][0] + ((const float*)&b4)[0]),
                 elu_(dacc[gt][1] + ((const float*)&b4)[1]),
                 elu_(dacc[gt][2] + ((const float*)&b4)[2]),
                 elu_(dacc[gt][3] + ((const float*)&b4)[3]));
        }
    }
}

// ---------------- fused: node mix + LN_G + dense_g, 4 t per block (verified r19) ----------------
__global__ __launch_bounds__(256) void nodemix_dense2(const unsigned short* __restrict__ d1,
                                                      const unsigned short* __restrict__ padj,
                                                      const float* __restrict__ gamma,
                                                      const float* __restrict__ beta,
                                                      const float* __restrict__ embs_g,
                                                      const unsigned short* __restrict__ pWg,
                                                      const float* __restrict__ b_g,
                                                      unsigned short* __restrict__ d2)
{
    __shared__ __align__(16) char smem[49920];
    unsigned short* sAdj = (unsigned short*)smem;             // [64][72]  = 9216
    unsigned short* sXT  = (unsigned short*)(smem + 9216);    // [64][104] -> 22528
    unsigned short* sA2  = (unsigned short*)(smem + 22528);   // [64][104] -> 35840
    unsigned short* sWg  = (unsigned short*)(smem + 35840);   // [64][104] -> 49152
    float*          sBg  = (float*)(smem + 49152);            // -> 49408
    float*          sGB  = (float*)(smem + 49408);            // -> 49920

    const int f  = blockIdx.x & 15;
    const int tq = (blockIdx.x >> 4) & 31;
    const int b  = blockIdx.x >> 9;
    const int t0 = tq * 4;
    const int tid = threadIdx.x, lane = tid & 63, w = tid >> 6;
    const int r16 = lane & 15, q = lane >> 4;

    if (tid < 64) sBg[tid] = b_g[tid];
    if (tid >= 64 && tid < 128) sGB[tid - 64] = gamma[tid - 64];
    if (tid >= 128 && tid < 192) sGB[tid - 64] = beta[tid - 128];
    for (int idx = tid; idx < 576; idx += 256)
        reinterpret_cast<ushort8*>(sAdj)[idx] = reinterpret_cast<const ushort8*>(padj)[idx];
    for (int idx = tid; idx < 832; idx += 256)
        reinterpret_cast<ushort8*>(sWg)[idx] = reinterpret_cast<const ushort8*>(pWg)[idx];
    for (int idx = tid; idx < 192; idx += 256) {
        int m = idx / 3, k8 = idx - m * 3;
        ushort8 z = {0,0,0,0,0,0,0,0};
        *reinterpret_cast<ushort8*>(&sA2[m * 104 + 72 + k8 * 8]) = z;
    }

    const int pn = tid >> 2, ph = (tid & 3) * 16;
    const int em = tid >> 2, ec = (tid & 3) * 2;
    ushort8 xr0, xr1;
    float2  er;
    {
        const unsigned short* pg = d1 + (((((size_t)b * T_ + t0) * F_) + f) << 12);
        xr0 = *reinterpret_cast<const ushort8*>(&pg[pn * 64 + ph]);
        xr1 = *reinterpret_cast<const ushort8*>(&pg[pn * 64 + ph + 8]);
        er  = *reinterpret_cast<const float2*>(&embs_g[((((size_t)(b * 64 + em)) * T_ + t0) * F_ + f) * 8 + ec]);
    }

    for (int tt = 0; tt < 4; ++tt) {
        const int t = t0 + tt;

        {
#pragma unroll
            for (int i = 0; i < 8; ++i) sXT[(ph + i) * 104 + pn] = xr0[i];
#pragma unroll
            for (int i = 0; i < 8; ++i) sXT[(ph + 8 + i) * 104 + pn] = xr1[i];
            *reinterpret_cast<unsigned*>(&sA2[em * 104 + 64 + ec]) = pk2(er.x, er.y);
        }
        if (tt < 3) {
            const unsigned short* pg = d1 + (((((size_t)b * T_ + t + 1) * F_) + f) << 12);
            xr0 = *reinterpret_cast<const ushort8*>(&pg[pn * 64 + ph]);
            xr1 = *reinterpret_cast<const ushort8*>(&pg[pn * 64 + ph + 8]);
            er  = *reinterpret_cast<const float2*>(&embs_g[((((size_t)(b * 64 + em)) * T_ + t + 1) * F_ + f) * 8 + ec]);
        }
        __syncthreads();

        f32x4 acc[4];
#pragma unroll
        for (int j = 0; j < 4; j++) acc[j] = {0.f, 0.f, 0.f, 0.f};
#pragma unroll
        for (int ks = 0; ks < 2; ++ks) {
            f16x8 af = *reinterpret_cast<const f16x8*>(&sAdj[(w * 16 + r16) * 72 + ks * 32 + q * 8]);
#pragma unroll
            for (int ht = 0; ht < 4; ++ht) {
                f16x8 xf = *reinterpret_cast<const f16x8*>(&sXT[(ht * 16 + r16) * 104 + ks * 32 + q * 8]);
                acc[ht] = __builtin_amdgcn_mfma_f32_16x16x32_f16(xf, af, acc[ht], 0, 0, 0);
            }
        }

        const int m = w * 16 + r16;
        float s = 0.f, qq = 0.f;
#pragma unroll
        for (int ht = 0; ht < 4; ++ht)
#pragma unroll
            for (int r = 0; r < 4; ++r) { float v = acc[ht][r]; s += v; qq += v * v; }
        s += __shfl_xor(s, 16, 64); qq += __shfl_xor(qq, 16, 64);
        s += __shfl_xor(s, 32, 64); qq += __shfl_xor(qq, 32, 64);
        float mean = s * (1.f / 64.f);
        float var  = qq * (1.f / 64.f) - mean * mean;
        float rstd = rsqrtf(var + 1e-5f);

#pragma unroll
        for (int ht = 0; ht < 4; ++ht) {
            float4 g4  = *reinterpret_cast<const float4*>(&sGB[ht * 16 + q * 4]);
            float4 be4 = *reinterpret_cast<const float4*>(&sGB[64 + ht * 16 + q * 4]);
            st4h(&sA2[m * 104 + ht * 16 + q * 4],
                 (acc[ht][0] - mean) * rstd * ((const float*)&g4)[0] + ((const float*)&be4)[0],
                 (acc[ht][1] - mean) * rstd * ((const float*)&g4)[1] + ((const float*)&be4)[1],
                 (acc[ht][2] - mean) * rstd * ((const float*)&g4)[2] + ((const float*)&be4)[2],
                 (acc[ht][3] - mean) * rstd * ((const float*)&g4)[3] + ((const float*)&be4)[3]);
        }
        __syncthreads();

        f32x4 dacc[4];
#pragma unroll
        for (int j = 0; j < 4; j++) dacc[j] = {0.f, 0.f, 0.f, 0.f};
#pragma unroll
        for (int ks = 0; ks < 3; ++ks) {
            const int ko = ks * 32 + q * 8;
            f16x8 aw = *reinterpret_cast<const f16x8*>(&sWg[(w * 16 + r16) * 104 + ko]);
#pragma unroll
            for (int mt = 0; mt < 4; ++mt) {
                f16x8 bx = *reinterpret_cast<const f16x8*>(&sA2[(mt * 16 + r16) * 104 + ko]);
                dacc[mt] = __builtin_amdgcn_mfma_f32_16x16x32_f16(aw, bx, dacc[mt], 0, 0, 0);
            }
        }

        float4 b4 = *reinterpret_cast<const float4*>(&sBg[w * 16 + q * 4]);
#pragma unroll
        for (int mt = 0; mt < 4; ++mt) {
            const int mm = mt * 16 + r16;
            const size_t row = (((size_t)(b * 64 + mm) * T_ + t) * F_ + f);
            st4h(&d2[row * H_ + w * 16 + q * 4],
                 elu_(dacc[mt][0] + b4.x), elu_(dacc[mt][1] + b4.y),
                 elu_(dacc[mt][2] + b4.z), elu_(dacc[mt][3] + b4.w));
        }
        __syncthreads();
    }
}

// ---------------- feature mix + LN + residual, 8 t per block (verified r14-r19) ----------------
__global__ __launch_bounds__(256) void featmix_v3(const unsigned short* __restrict__ e,
                                                  const float* __restrict__ adjg,
                                                  const float* __restrict__ gamma,
                                                  const float* __restrict__ beta,
                                                  const float* __restrict__ res,
                                                  float* __restrict__ out)
{
    __shared__ __align__(16) unsigned short se[8 * 16 * 64];

    const int t0 = (blockIdx.x & 15) * 8, bn = blockIdx.x >> 4;
    const int tid = threadIdx.x;

    {
        int f = tid >> 4, c4 = (tid & 15) * 4;
#pragma unroll
        for (int tl = 0; tl < 8; ++tl)
            *reinterpret_cast<ushort4*>(&se[tl * 1024 + f * 64 + c4]) =
                *reinterpret_cast<const ushort4*>(&e[(((size_t)bn * T_ + t0 + tl) * F_ + f) * H_ + c4]);
    }
    __syncthreads();

    const int g = tid >> 4, hq = tid & 15;
    float ag[16];
#pragma unroll
    for (int f = 0; f < 16; ++f) ag[f] = adjg[g * 16 + f];
    float gm0 = gamma[hq * 4 + 0], gm1 = gamma[hq * 4 + 1], gm2 = gamma[hq * 4 + 2], gm3 = gamma[hq * 4 + 3];
    float be0 = beta[hq * 4 + 0],  be1 = beta[hq * 4 + 1],  be2 = beta[hq * 4 + 2],  be3 = beta[hq * 4 + 3];

    for (int tl = 0; tl < 8; ++tl) {
        float a0 = 0.f, a1 = 0.f, a2 = 0.f, a3 = 0.f;
#pragma unroll
        for (int f = 0; f < 16; ++f) {
            ushort4 dv = *reinterpret_cast<const ushort4*>(&se[tl * 1024 + f * 64 + hq * 4]);
            float av = ag[f];
            a0 = fmaf(av, h2f(dv.x), a0);
            a1 = fmaf(av, h2f(dv.y), a1);
            a2 = fmaf(av, h2f(dv.z), a2);
            a3 = fmaf(av, h2f(dv.w), a3);
        }
        float s  = a0 + a1 + a2 + a3;
        float qv = a0*a0 + a1*a1 + a2*a2 + a3*a3;
#pragma unroll
        for (int m = 1; m < 16; m <<= 1) { s += __shfl_xor(s, m, 64); qv += __shfl_xor(qv, m, 64); }
        float mean = s * (1.f / 64.f);
        float var  = qv * (1.f / 64.f) - mean * mean;
        float rstd = rsqrtf(var + 1e-5f);

        const size_t o = (((size_t)bn * T_ + t0 + tl) * F_ + g) * H_ + hq * 4;
        float4 rv = *reinterpret_cast<const float4*>(res + o);
        float4 ov;
        ov.x = (a0 - mean) * rstd * gm0 + be0 + rv.x;
        ov.y = (a1 - mean) * rstd * gm1 + be1 + rv.y;
        ov.z = (a2 - mean) * rstd * gm2 + be2 + rv.z;
        ov.w = (a3 - mean) * rstd * gm3 + be3 + rv.w;
        *reinterpret_cast<float4*>(out + o) = ov;
    }
}

extern "C" void kernel_launch(void* const* d_in, const int* in_sizes, int n_in,
                              void* d_out, int out_size, void* d_ws, size_t ws_size,
                              hipStream_t stream)
{
    const float* h_in    = (const float*)d_in[0];
    const float* embs_G  = (const float*)d_in[2];
    const float* embs_g  = (const float*)d_in[3];
    const float* adj_G   = (const float*)d_in[4];
    const float* adj_g   = (const float*)d_in[5];
    const float* Wt0 = (const float*)d_in[6];  const float* bt0 = (const float*)d_in[7];
    const float* Wt1 = (const float*)d_in[8];  const float* bt1 = (const float*)d_in[9];
    const float* Wt2 = (const float*)d_in[10]; const float* bt2 = (const float*)d_in[11];
    const float* gamma_t = (const float*)d_in[12]; const float* beta_t = (const float*)d_in[13];
    const float* W_G = (const float*)d_in[14]; const float* b_G = (const float*)d_in[15];
    const float* gamma_G = (const float*)d_in[16]; const float* beta_G = (const float*)d_in[17];
    const float* W_g = (const float*)d_in[18]; const float* b_g = (const float*)d_in[19];
    const float* gamma_g = (const float*)d_in[20]; const float* beta_g = (const float*)d_in[21];

    float* out = (float*)d_out;
    char*  ws  = (char*)d_ws;
    unsigned short* d1 = (unsigned short*)ws;                          // 64 MiB (paged layout)
    unsigned short* d2 = (unsigned short*)(ws + ((size_t)64 << 20));   // 64 MiB

    unsigned short* prep = (unsigned short*)(ws + ((size_t)192 << 20));
    unsigned short* pw   = prep;                 // 3*16*64*192
    unsigned short* pWG  = prep + 589824;
    unsigned short* pWg  = pWG + 6656;
    unsigned short* padj = pWg + 6656;

    prep_all<<<49, 256, 0, stream>>>(Wt0, Wt1, Wt2, adj_G, W_G, W_g, pw, padj, pWG, pWg);

    conv_chain<<<4096, 512, 0, stream>>>(h_in, pw, bt0, bt1, bt2, gamma_t, beta_t,
                                         embs_G, pWG, b_G, d1);
    nodemix_dense2<<<2048, 256, 0, stream>>>(d1, padj, gamma_G, beta_G,
                                             embs_g, pWg, b_g, d2);
    featmix_v3<<<4096, 256, 0, stream>>>(d2, adj_g, gamma_g, beta_g, h_in, out);
}

// Round 21
// 223.499 us; speedup vs baseline: 1.0264x; 1.0264x over previous
//
#include <hip/hip_runtime.h>

#define BN_ 256
#define T_  128
#define F_  16
#define H_  64

using f16x8   = __attribute__((ext_vector_type(8))) _Float16;
using f32x4   = __attribute__((ext_vector_type(4))) float;
using ushort8 = __attribute__((ext_vector_type(8))) unsigned short;

__device__ __forceinline__ float elu_(float x) { return x > 0.f ? x : __expf(x) - 1.f; }
__device__ __forceinline__ unsigned short f2h(float x) {
    union { _Float16 h; unsigned short u; } v; v.h = (_Float16)x; return v.u;
}
__device__ __forceinline__ float h2f(unsigned short u) {
    union { unsigned short u; _Float16 h; } v; v.u = u; return (float)v.h;
}
__device__ __forceinline__ unsigned pk2(float a, float b) {
    auto h = __builtin_amdgcn_cvt_pkrtz(a, b);
    unsigned u; __builtin_memcpy(&u, &h, 4); return u;
}
__device__ __forceinline__ void st4h(unsigned short* p, float a, float b, float c, float d) {
    uint2 v; v.x = pk2(a, b); v.y = pk2(c, d);
    *reinterpret_cast<uint2*>(p) = v;
}

// ---------------- prep: conv weights -> fp16 transposed [l][f][g][192]; block 48 does small tensors ----------------
__global__ __launch_bounds__(256) void prep_all(const float* __restrict__ Wt0,
                                                const float* __restrict__ Wt1,
                                                const float* __restrict__ Wt2,
                                                const float* __restrict__ adjG,
                                                const float* __restrict__ W_G,
                                                const float* __restrict__ W_g,
                                                unsigned short* __restrict__ pw,
                                                unsigned short* __restrict__ padj,
                                                unsigned short* __restrict__ pWG,
                                                unsigned short* __restrict__ pWg)
{
    const int tid = threadIdx.x;
    if (blockIdx.x == 48) {
        for (int idx = tid; idx < 4608; idx += 256) {
            int m = idx / 72, n = idx - m * 72;
            padj[idx] = (n < 64) ? f2h(adjG[m * 64 + n]) : (unsigned short)0;
        }
        for (int idx = tid; idx < 6656; idx += 256) {
            int g = idx / 104, k = idx - g * 104;
            pWG[idx] = (k < 80) ? f2h(W_G[k * 64 + g]) : (unsigned short)0;
        }
        for (int idx = tid; idx < 6656; idx += 256) {
            int g = idx / 104, k = idx - g * 104;
            pWg[idx] = (k < 72) ? f2h(W_g[k * 64 + g]) : (unsigned short)0;
        }
        return;
    }
    __shared__ unsigned short sW[64 * 200];
    const int lf = blockIdx.x, l = lf >> 4, f = lf & 15;
    const float* W = (l == 0) ? Wt0 : ((l == 1) ? Wt1 : Wt2);

    for (int idx = tid; idx < 3 * 4096; idx += 256) {
        int tap = idx >> 12, rem = idx & 4095;
        int h = rem >> 6, g = rem & 63;
        sW[g * 200 + tap * 64 + h] = f2h(W[(size_t)(tap * 16 + f) * 4096 + rem]);
    }
    __syncthreads();
    for (int idx = tid; idx < 64 * 24; idx += 256) {
        int g = idx / 24, k8 = idx - g * 24;
        *reinterpret_cast<ushort8*>(&pw[((size_t)lf * 64 + g) * 192 + k8 * 8]) =
            *reinterpret_cast<const ushort8*>(&sW[g * 200 + k8 * 8]);
    }
}

// ---------------- fused: tconv x3 (+LN_t) + dense_G per (bn,f); 8 waves; r19-verified strides ----------------
// tile stride 80, sW stride 208. d1 layout: pages [b][t][f][n][64h]
__global__ __launch_bounds__(512) void conv_chain(const float* __restrict__ in,
                                                  const unsigned short* __restrict__ pw,
                                                  const float* __restrict__ bt0,
                                                  const float* __restrict__ bt1,
                                                  const float* __restrict__ bt2,
                                                  const float* __restrict__ gamma,
                                                  const float* __restrict__ beta,
                                                  const float* __restrict__ embs_G,
                                                  const unsigned short* __restrict__ pWG,
                                                  const float* __restrict__ b_G,
                                                  unsigned short* __restrict__ d1)
{
    __shared__ __align__(16) char smem[49920];
    unsigned short* tile = (unsigned short*)smem;             // [136][80] = 21760 B
    unsigned short* sW   = (unsigned short*)(smem + 21760);   // [64][208] = 26624 B -> 48384
    float*          sCst = (float*)(smem + 48384);            // [6][64] = 1536 -> 49920
    unsigned short* sA1  = (unsigned short*)smem;             // [128][104] overlay (0..26624)
    unsigned short* sWG  = (unsigned short*)(smem + 26624);   // [64][104] overlay (26624..39936)

    const int f   = blockIdx.x & 15;
    const int bn  = blockIdx.x >> 4;
    const int tid = threadIdx.x;
    const int lane = tid & 63, w = tid >> 6;
    const int r16 = lane & 15, q = lane >> 4;

    const int et = tid >> 2, ee = (tid & 3) * 4;
    float4 ereg = *reinterpret_cast<const float4*>(
        embs_G + ((((size_t)bn * T_ + et) * F_ + f) * 16 + ee));

    if (tid < 64) {
        sCst[0 * 64 + tid] = bt0[f * 64 + tid];
        sCst[1 * 64 + tid] = bt1[f * 64 + tid];
        sCst[2 * 64 + tid] = bt2[f * 64 + tid];
        sCst[3 * 64 + tid] = gamma[tid];
        sCst[4 * 64 + tid] = beta[tid];
        sCst[5 * 64 + tid] = b_G[tid];
    }
    // halo rows (0..3, 132..135) zero
    if (tid < 128) {
        int hr = tid >> 4;
        int r = (hr < 4) ? hr : 128 + hr;
        uint2 z = {0, 0};
        *reinterpret_cast<uint2*>(&tile[r * 80 + (tid & 15) * 4]) = z;
    }
    // body rows: exactly 4 branch-free iterations
#pragma unroll
    for (int it = 0; it < 4; ++it) {
        int idx = it * 512 + tid;
        int r = idx >> 4, h4 = (idx & 15) * 4;
        float4 x = *reinterpret_cast<const float4*>(in + (((size_t)bn * T_ + r) * F_ + f) * H_ + h4);
        st4h(&tile[(r + 4) * 80 + h4], x.x, x.y, x.z, x.w);
    }
    {
        const unsigned short* wsrc = pw + (size_t)f * 64 * 192;
        for (int idx = tid; idx < 1536; idx += 512) {
            int g = idx / 24, k8 = idx - g * 24;
            *reinterpret_cast<ushort8*>(&sW[g * 208 + k8 * 8]) =
                *reinterpret_cast<const ushort8*>(&wsrc[g * 192 + k8 * 8]);
        }
    }
    __syncthreads();

    float vv[4][4];

#pragma unroll
    for (int l = 0; l < 3; ++l) {
        const int dil = 1 << l;

        ushort8 wreg[3];
        if (l < 2) {
            const unsigned short* wsrc = pw + ((size_t)((l + 1) * 16 + f) * 64) * 192;
#pragma unroll
            for (int j = 0; j < 3; ++j) {
                int idx = j * 512 + tid, g = idx / 24, k8 = idx - g * 24;
                wreg[j] = *reinterpret_cast<const ushort8*>(&wsrc[g * 192 + k8 * 8]);
            }
        }
        ushort8 wgreg[2];
        if (l == 2) {
#pragma unroll
            for (int j = 0; j < 2; ++j) {
                int idx = j * 512 + tid;
                if (idx < 832) wgreg[j] = reinterpret_cast<const ushort8*>(pWG)[idx];
            }
        }

        f32x4 acc[4];
#pragma unroll
        for (int j = 0; j < 4; j++) acc[j] = {0.f, 0.f, 0.f, 0.f};

#pragma unroll
        for (int tap = 0; tap < 3; ++tap) {
            const int row0 = w * 16 + r16 + 4 + (tap - 1) * dil;
#pragma unroll
            for (int ks = 0; ks < 2; ++ks) {
                const int ko = ks * 32 + q * 8;
                f16x8 a0 = *reinterpret_cast<const f16x8*>(&tile[row0 * 80 + ko]);
                const int kb = tap * 64 + ko;
                f16x8 b0 = *reinterpret_cast<const f16x8*>(&sW[(r16     ) * 208 + kb]);
                f16x8 b1 = *reinterpret_cast<const f16x8*>(&sW[(r16 + 16) * 208 + kb]);
                f16x8 b2 = *reinterpret_cast<const f16x8*>(&sW[(r16 + 32) * 208 + kb]);
                f16x8 b3 = *reinterpret_cast<const f16x8*>(&sW[(r16 + 48) * 208 + kb]);
                acc[0] = __builtin_amdgcn_mfma_f32_16x16x32_f16(b0, a0, acc[0], 0, 0, 0);
                acc[1] = __builtin_amdgcn_mfma_f32_16x16x32_f16(b1, a0, acc[1], 0, 0, 0);
                acc[2] = __builtin_amdgcn_mfma_f32_16x16x32_f16(b2, a0, acc[2], 0, 0, 0);
                acc[3] = __builtin_amdgcn_mfma_f32_16x16x32_f16(b3, a0, acc[3], 0, 0, 0);
            }
        }

#pragma unroll
        for (int gt = 0; gt < 4; ++gt) {
            float4 b4 = *reinterpret_cast<const float4*>(&sCst[l * 64 + gt * 16 + q * 4]);
#pragma unroll
            for (int r = 0; r < 4; ++r) vv[gt][r] = elu_(acc[gt][r] + ((const float*)&b4)[r]);
        }
        if (l == 2) {
            float s = 0.f, qq = 0.f;
#pragma unroll
            for (int gt = 0; gt < 4; ++gt)
#pragma unroll
                for (int r = 0; r < 4; ++r) { float v = vv[gt][r]; s += v; qq += v * v; }
            s += __shfl_xor(s, 16, 64); qq += __shfl_xor(qq, 16, 64);
            s += __shfl_xor(s, 32, 64); qq += __shfl_xor(qq, 32, 64);
            float mean = s * (1.f / 64.f);
            float var  = qq * (1.f / 64.f) - mean * mean;
            float rstd = rsqrtf(var + 1e-5f);
#pragma unroll
            for (int gt = 0; gt < 4; ++gt) {
                float4 g4 = *reinterpret_cast<const float4*>(&sCst[3 * 64 + gt * 16 + q * 4]);
                float4 be4 = *reinterpret_cast<const float4*>(&sCst[4 * 64 + gt * 16 + q * 4]);
#pragma unroll
                for (int r = 0; r < 4; ++r)
                    vv[gt][r] = (vv[gt][r] - mean) * rstd * ((const float*)&g4)[r] + ((const float*)&be4)[r];
            }
        }
        __syncthreads();

        if (l < 2) {
            const int t = w * 16 + r16;
#pragma unroll
            for (int gt = 0; gt < 4; ++gt)
                st4h(&tile[(t + 4) * 80 + gt * 16 + q * 4],
                     vv[gt][0], vv[gt][1], vv[gt][2], vv[gt][3]);
#pragma unroll
            for (int j = 0; j < 3; ++j) {
                int idx = j * 512 + tid, g = idx / 24, k8 = idx - g * 24;
                *reinterpret_cast<ushort8*>(&sW[g * 208 + k8 * 8]) = wreg[j];
            }
            __syncthreads();
        } else {
            const int t = w * 16 + r16;
#pragma unroll
            for (int gt = 0; gt < 4; ++gt)
                st4h(&sA1[t * 104 + gt * 16 + q * 4],
                     vv[gt][0], vv[gt][1], vv[gt][2], vv[gt][3]);
            st4h(&sA1[et * 104 + 64 + ee], ereg.x, ereg.y, ereg.z, ereg.w);
            if (tid < 256) {
                int r = tid >> 1, half = tid & 1;
                ushort8 z = {0,0,0,0,0,0,0,0};
                *reinterpret_cast<ushort8*>(&sA1[r * 104 + 80 + half * 8]) = z;
            }
#pragma unroll
            for (int j = 0; j < 2; ++j) {
                int idx = j * 512 + tid;
                if (idx < 832) reinterpret_cast<ushort8*>(sWG)[idx] = wgreg[j];
            }
            __syncthreads();
        }
    }

    f32x4 dacc[4];
#pragma unroll
    for (int j = 0; j < 4; j++) dacc[j] = {0.f, 0.f, 0.f, 0.f};

#pragma unroll
    for (int ks = 0; ks < 3; ++ks) {
        const int ko = ks * 32 + q * 8;
        f16x8 a0 = *reinterpret_cast<const f16x8*>(&sA1[(w * 16 + r16) * 104 + ko]);
#pragma unroll
        for (int gt = 0; gt < 4; ++gt) {
            f16x8 bb = *reinterpret_cast<const f16x8*>(&sWG[(gt * 16 + r16) * 104 + ko]);
            dacc[gt] = __builtin_amdgcn_mfma_f32_16x16x32_f16(bb, a0, dacc[gt], 0, 0, 0);
        }
    }

    {
        const int t = w * 16 + r16;
        const int b = bn >> 6, n = bn & 63;
        const size_t ob = ((((size_t)b * T_ + t) * F_ + f) << 12) + (size_t)n * 64;
#pragma unroll
        for (int gt = 0; gt < 4; ++gt) {
            float4 b4 = *reinterpret_cast<const float4*>(&sCst[5 * 64 + gt * 16 + q * 4]);
            st4h(&d1[ob + gt * 16 + q * 4],
                 elu_(dacc[gt][0] + ((const float*)&b4)[0]),
                 elu_(dacc[gt][1] + ((const float*)&b4)[1]),
                 elu_(dacc[gt][2] + ((const float*)&b4)[2]),
                 elu_(dacc[gt][3] + ((const float*)&b4)[3]));
        }
    }
}

// ---------------- fused: node mix + LN_G + dense_g, 4 t per block (verified r19) ----------------
__global__ __launch_bounds__(256) void nodemix_dense2(const unsigned short* __restrict__ d1,
                                                      const unsigned short* __restrict__ padj,
                                                      const float* __restrict__ gamma,
                                                      const float* __restrict__ beta,
                                                      const float* __restrict__ embs_g,
                                                      const unsigned short* __restrict__ pWg,
                                                      const float* __restrict__ b_g,
                                                      unsigned short* __restrict__ d2)
{
    __shared__ __align__(16) char smem[49920];
    unsigned short* sAdj = (unsigned short*)smem;             // [64][72]  = 9216
    unsigned short* sXT  = (unsigned short*)(smem + 9216);    // [64][104] -> 22528
    unsigned short* sA2  = (unsigned short*)(smem + 22528);   // [64][104] -> 35840
    unsigned short* sWg  = (unsigned short*)(smem + 35840);   // [64][104] -> 49152
    float*          sBg  = (float*)(smem + 49152);            // -> 49408
    float*          sGB  = (float*)(smem + 49408);            // -> 49920

    const int f  = blockIdx.x & 15;
    const int tq = (blockIdx.x >> 4) & 31;
    const int b  = blockIdx.x >> 9;
    const int t0 = tq * 4;
    const int tid = threadIdx.x, lane = tid & 63, w = tid >> 6;
    const int r16 = lane & 15, q = lane >> 4;

    if (tid < 64) sBg[tid] = b_g[tid];
    if (tid >= 64 && tid < 128) sGB[tid - 64] = gamma[tid - 64];
    if (tid >= 128 && tid < 192) sGB[tid - 64] = beta[tid - 128];
    for (int idx = tid; idx < 576; idx += 256)
        reinterpret_cast<ushort8*>(sAdj)[idx] = reinterpret_cast<const ushort8*>(padj)[idx];
    for (int idx = tid; idx < 832; idx += 256)
        reinterpret_cast<ushort8*>(sWg)[idx] = reinterpret_cast<const ushort8*>(pWg)[idx];
    for (int idx = tid; idx < 192; idx += 256) {
        int m = idx / 3, k8 = idx - m * 3;
        ushort8 z = {0,0,0,0,0,0,0,0};
        *reinterpret_cast<ushort8*>(&sA2[m * 104 + 72 + k8 * 8]) = z;
    }

    const int pn = tid >> 2, ph = (tid & 3) * 16;
    const int em = tid >> 2, ec = (tid & 3) * 2;
    ushort8 xr0, xr1;
    float2  er;
    {
        const unsigned short* pg = d1 + (((((size_t)b * T_ + t0) * F_) + f) << 12);
        xr0 = *reinterpret_cast<const ushort8*>(&pg[pn * 64 + ph]);
        xr1 = *reinterpret_cast<const ushort8*>(&pg[pn * 64 + ph + 8]);
        er  = *reinterpret_cast<const float2*>(&embs_g[((((size_t)(b * 64 + em)) * T_ + t0) * F_ + f) * 8 + ec]);
    }

    for (int tt = 0; tt < 4; ++tt) {
        const int t = t0 + tt;

        {
#pragma unroll
            for (int i = 0; i < 8; ++i) sXT[(ph + i) * 104 + pn] = xr0[i];
#pragma unroll
            for (int i = 0; i < 8; ++i) sXT[(ph + 8 + i) * 104 + pn] = xr1[i];
            *reinterpret_cast<unsigned*>(&sA2[em * 104 + 64 + ec]) = pk2(er.x, er.y);
        }
        if (tt < 3) {
            const unsigned short* pg = d1 + (((((size_t)b * T_ + t + 1) * F_) + f) << 12);
            xr0 = *reinterpret_cast<const ushort8*>(&pg[pn * 64 + ph]);
            xr1 = *reinterpret_cast<const ushort8*>(&pg[pn * 64 + ph + 8]);
            er  = *reinterpret_cast<const float2*>(&embs_g[((((size_t)(b * 64 + em)) * T_ + t + 1) * F_ + f) * 8 + ec]);
        }
        __syncthreads();

        f32x4 acc[4];
#pragma unroll
        for (int j = 0; j < 4; j++) acc[j] = {0.f, 0.f, 0.f, 0.f};
#pragma unroll
        for (int ks = 0; ks < 2; ++ks) {
            f16x8 af = *reinterpret_cast<const f16x8*>(&sAdj[(w * 16 + r16) * 72 + ks * 32 + q * 8]);
#pragma unroll
            for (int ht = 0; ht < 4; ++ht) {
                f16x8 xf = *reinterpret_cast<const f16x8*>(&sXT[(ht * 16 + r16) * 104 + ks * 32 + q * 8]);
                acc[ht] = __builtin_amdgcn_mfma_f32_16x16x32_f16(xf, af, acc[ht], 0, 0, 0);
            }
        }

        const int m = w * 16 + r16;
        float s = 0.f, qq = 0.f;
#pragma unroll
        for (int ht = 0; ht < 4; ++ht)
#pragma unroll
            for (int r = 0; r < 4; ++r) { float v = acc[ht][r]; s += v; qq += v * v; }
        s += __shfl_xor(s, 16, 64); qq += __shfl_xor(qq, 16, 64);
        s += __shfl_xor(s, 32, 64); qq += __shfl_xor(qq, 32, 64);
        float mean = s * (1.f / 64.f);
        float var  = qq * (1.f / 64.f) - mean * mean;
        float rstd = rsqrtf(var + 1e-5f);

#pragma unroll
        for (int ht = 0; ht < 4; ++ht) {
            float4 g4  = *reinterpret_cast<const float4*>(&sGB[ht * 16 + q * 4]);
            float4 be4 = *reinterpret_cast<const float4*>(&sGB[64 + ht * 16 + q * 4]);
            st4h(&sA2[m * 104 + ht * 16 + q * 4],
                 (acc[ht][0] - mean) * rstd * ((const float*)&g4)[0] + ((const float*)&be4)[0],
                 (acc[ht][1] - mean) * rstd * ((const float*)&g4)[1] + ((const float*)&be4)[1],
                 (acc[ht][2] - mean) * rstd * ((const float*)&g4)[2] + ((const float*)&be4)[2],
                 (acc[ht][3] - mean) * rstd * ((const float*)&g4)[3] + ((const float*)&be4)[3]);
        }
        __syncthreads();

        f32x4 dacc[4];
#pragma unroll
        for (int j = 0; j < 4; j++) dacc[j] = {0.f, 0.f, 0.f, 0.f};
#pragma unroll
        for (int ks = 0; ks < 3; ++ks) {
            const int ko = ks * 32 + q * 8;
            f16x8 aw = *reinterpret_cast<const f16x8*>(&sWg[(w * 16 + r16) * 104 + ko]);
#pragma unroll
            for (int mt = 0; mt < 4; ++mt) {
                f16x8 bx = *reinterpret_cast<const f16x8*>(&sA2[(mt * 16 + r16) * 104 + ko]);
                dacc[mt] = __builtin_amdgcn_mfma_f32_16x16x32_f16(aw, bx, dacc[mt], 0, 0, 0);
            }
        }

        float4 b4 = *reinterpret_cast<const float4*>(&sBg[w * 16 + q * 4]);
#pragma unroll
        for (int mt = 0; mt < 4; ++mt) {
            const int mm = mt * 16 + r16;
            const size_t row = (((size_t)(b * 64 + mm) * T_ + t) * F_ + f);
            st4h(&d2[row * H_ + w * 16 + q * 4],
                 elu_(dacc[mt][0] + b4.x), elu_(dacc[mt][1] + b4.y),
                 elu_(dacc[mt][2] + b4.z), elu_(dacc[mt][3] + b4.w));
        }
        __syncthreads();
    }
}

// ---------------- feature mix + LN + residual, 8 t per block (verified r14-r19) ----------------
__global__ __launch_bounds__(256) void featmix_v3(const unsigned short* __restrict__ e,
                                                  const float* __restrict__ adjg,
                                                  const float* __restrict__ gamma,
                                                  const float* __restrict__ beta,
                                                  const float* __restrict__ res,
                                                  float* __restrict__ out)
{
    __shared__ __align__(16) unsigned short se[8 * 16 * 64];

    const int t0 = (blockIdx.x & 15) * 8, bn = blockIdx.x >> 4;
    const int tid = threadIdx.x;

    {
        int f = tid >> 4, c4 = (tid & 15) * 4;
#pragma unroll
        for (int tl = 0; tl < 8; ++tl)
            *reinterpret_cast<ushort4*>(&se[tl * 1024 + f * 64 + c4]) =
                *reinterpret_cast<const ushort4*>(&e[(((size_t)bn * T_ + t0 + tl) * F_ + f) * H_ + c4]);
    }
    __syncthreads();

    const int g = tid >> 4, hq = tid & 15;
    float ag[16];
#pragma unroll
    for (int f = 0; f < 16; ++f) ag[f] = adjg[g * 16 + f];
    float gm0 = gamma[hq * 4 + 0], gm1 = gamma[hq * 4 + 1], gm2 = gamma[hq * 4 + 2], gm3 = gamma[hq * 4 + 3];
    float be0 = beta[hq * 4 + 0],  be1 = beta[hq * 4 + 1],  be2 = beta[hq * 4 + 2],  be3 = beta[hq * 4 + 3];

    for (int tl = 0; tl < 8; ++tl) {
        float a0 = 0.f, a1 = 0.f, a2 = 0.f, a3 = 0.f;
#pragma unroll
        for (int f = 0; f < 16; ++f) {
            ushort4 dv = *reinterpret_cast<const ushort4*>(&se[tl * 1024 + f * 64 + hq * 4]);
            float av = ag[f];
            a0 = fmaf(av, h2f(dv.x), a0);
            a1 = fmaf(av, h2f(dv.y), a1);
            a2 = fmaf(av, h2f(dv.z), a2);
            a3 = fmaf(av, h2f(dv.w), a3);
        }
        float s  = a0 + a1 + a2 + a3;
        float qv = a0*a0 + a1*a1 + a2*a2 + a3*a3;
#pragma unroll
        for (int m = 1; m < 16; m <<= 1) { s += __shfl_xor(s, m, 64); qv += __shfl_xor(qv, m, 64); }
        float mean = s * (1.f / 64.f);
        float var  = qv * (1.f / 64.f) - mean * mean;
        float rstd = rsqrtf(var + 1e-5f);

        const size_t o = (((size_t)bn * T_ + t0 + tl) * F_ + g) * H_ + hq * 4;
        float4 rv = *reinterpret_cast<const float4*>(res + o);
        float4 ov;
        ov.x = (a0 - mean) * rstd * gm0 + be0 + rv.x;
        ov.y = (a1 - mean) * rstd * gm1 + be1 + rv.y;
        ov.z = (a2 - mean) * rstd * gm2 + be2 + rv.z;
        ov.w = (a3 - mean) * rstd * gm3 + be3 + rv.w;
        *reinterpret_cast<float4*>(out + o) = ov;
    }
}

extern "C" void kernel_launch(void* const* d_in, const int* in_sizes, int n_in,
                              void* d_out, int out_size, void* d_ws, size_t ws_size,
                              hipStream_t stream)
{
    const float* h_in    = (const float*)d_in[0];
    const float* embs_G  = (const float*)d_in[2];
    const float* embs_g  = (const float*)d_in[3];
    const float* adj_G   = (const float*)d_in[4];
    const float* adj_g   = (const float*)d_in[5];
    const float* Wt0 = (const float*)d_in[6];  const float* bt0 = (const float*)d_in[7];
    const float* Wt1 = (const float*)d_in[8];  const float* bt1 = (const float*)d_in[9];
    const float* Wt2 = (const float*)d_in[10]; const float* bt2 = (const float*)d_in[11];
    const float* gamma_t = (const float*)d_in[12]; const float* beta_t = (const float*)d_in[13];
    const float* W_G = (const float*)d_in[14]; const float* b_G = (const float*)d_in[15];
    const float* gamma_G = (const float*)d_in[16]; const float* beta_G = (const float*)d_in[17];
    const float* W_g = (const float*)d_in[18]; const float* b_g = (const float*)d_in[19];
    const float* gamma_g = (const float*)d_in[20]; const float* beta_g = (const float*)d_in[21];

    float* out = (float*)d_out;
    char*  ws  = (char*)d_ws;
    unsigned short* d1 = (unsigned short*)ws;                          // 64 MiB (paged layout)
    unsigned short* d2 = (unsigned short*)(ws + ((size_t)64 << 20));   // 64 MiB

    unsigned short* prep = (unsigned short*)(ws + ((size_t)192 << 20));
    unsigned short* pw   = prep;                 // 3*16*64*192
    unsigned short* pWG  = prep + 589824;
    unsigned short* pWg  = pWG + 6656;
    unsigned short* padj = pWg + 6656;

    prep_all<<<49, 256, 0, stream>>>(Wt0, Wt1, Wt2, adj_G, W_G, W_g, pw, padj, pWG, pWg);

    conv_chain<<<4096, 512, 0, stream>>>(h_in, pw, bt0, bt1, bt2, gamma_t, beta_t,
                                         embs_G, pWG, b_G, d1);
    nodemix_dense2<<<2048, 256, 0, stream>>>(d1, padj, gamma_G, beta_G,
                                             embs_g, pWg, b_g, d2);
    featmix_v3<<<4096, 256, 0, stream>>>(d2, adj_g, gamma_g, beta_g, h_in, out);
}